// Round 5
// baseline (646.354 us; speedup 1.0000x reference)
//
#include <hip/hip_runtime.h>

// BertSelfAttention on MI355X: bf16 MFMA QKV GEMM + flash-style attention.
// B=8 S=1024 HID=1024 NH=16 HD=64. Softmax without max-subtraction (scores
// bounded ~|3.3|; exp2 safe in fp32).
// R5: 3 launches total. k_prep = convert + W-transpose fused. k_gemm = R3's
// proven dbuf structure; V-blocks write V^T directly via per-wave LDS
// transpose (k_transv deleted). k_attn = R4's spill-free 32-qrow design.

typedef __bf16 bf16x8 __attribute__((ext_vector_type(8)));
typedef float f32x16 __attribute__((ext_vector_type(16)));

__device__ __forceinline__ unsigned rne16(float x) {
  unsigned u = __builtin_bit_cast(unsigned, x);
  return (u + 0x7fffu + ((u >> 16) & 1u)) >> 16;
}
__device__ __forceinline__ unsigned packbf(float lo, float hi) {
  return rne16(lo) | (rne16(hi) << 16);
}
// fast pack (round-half-up) for softmax probabilities.
__device__ __forceinline__ unsigned packbf_fast(float lo, float hi) {
  unsigned ul = __builtin_bit_cast(unsigned, lo) + 0x8000u;
  unsigned uh = __builtin_bit_cast(unsigned, hi) + 0x8000u;
  return __builtin_amdgcn_perm(uh, ul, 0x07060302u);
}
// async global->LDS, 16B per lane; LDS dst is wave-uniform base + lane*16.
__device__ __forceinline__ void async16(void* l, const void* g) {
  __builtin_amdgcn_global_load_lds((const __attribute__((address_space(1))) void*)g,
                                   (__attribute__((address_space(3))) void*)l, 16, 0, 0);
}

// ---------------- fused: hidden fp32->bf16 (blocks 0..8191) + W transpose (8192..11263) ----
__global__ __launch_bounds__(256) void k_prep(const float* __restrict__ h,
                                              unsigned short* __restrict__ hbf,
                                              const float* __restrict__ Wq,
                                              const float* __restrict__ Wk,
                                              const float* __restrict__ Wv,
                                              unsigned short* __restrict__ wt) {
  __shared__ float t[32][33];
  int bid = blockIdx.x, tid = threadIdx.x;
  if (bid < 8192) {
    size_t i = (size_t)bid * 256 + tid;
    float4 v = ((const float4*)h)[i];
    uint2 r;
    r.x = packbf(v.x, v.y);
    r.y = packbf(v.z, v.w);
    ((uint2*)hbf)[i] = r;
  } else {
    int id = bid - 8192;           // 0..3071
    int which = id >> 10;
    int sub = id & 1023;
    int c0 = (sub & 31) * 32, k0 = (sub >> 5) * 32;
    const float* W = which == 0 ? Wq : (which == 1 ? Wk : Wv);
    int tx = tid & 31, ty = tid >> 5;
#pragma unroll
    for (int i = 0; i < 4; ++i) {
      int r = ty + i * 8;
      t[r][tx] = W[(size_t)(k0 + r) * 1024 + c0 + tx];
    }
    __syncthreads();
#pragma unroll
    for (int i = 0; i < 4; ++i) {
      int r = ty + i * 8;
      wt[((size_t)which * 1024 + c0 + r) * 1024 + k0 + tx] = (unsigned short)rne16(t[tx][r]);
    }
  }
}

// ---------------- QKV GEMM: [8192x1024] x [1024x3072]^T + bias ----------------
// Block tile 256x128, wave tile 128x64 (4x2 acc), BK=32, 32x32x16 MFMA,
// double-buffered LDS (R3 structure, measured 101.8us).
// q/k written as bf16 [b][h][s][d]; v written DIRECTLY as V^T [b][h][d][s]
// via per-wave LDS transpose in the epilogue.
__global__ __launch_bounds__(256, 2) void k_gemm(const unsigned short* __restrict__ A,
                                                 const unsigned short* __restrict__ Bm,
                                                 const float* __restrict__ bq,
                                                 const float* __restrict__ bk,
                                                 const float* __restrict__ bv,
                                                 unsigned short* __restrict__ qkv,
                                                 unsigned short* __restrict__ vt) {
  __shared__ __align__(16) char lds[49152];  // 2 x (A 16KB + B 8KB)
  int tid = threadIdx.x, w = tid >> 6, lane = tid & 63, l5 = lane & 31, q5 = lane >> 5;
  int wr = w >> 1, wc = w & 1;
  int m0 = blockIdx.x * 256, n0 = blockIdx.y * 128;

  f32x16 acc[4][2];
#pragma unroll
  for (int i = 0; i < 4; ++i)
#pragma unroll
    for (int j = 0; j < 2; ++j)
#pragma unroll
      for (int e = 0; e < 16; ++e) acc[i][j][e] = 0.f;

  auto stage = [&](int kt, char* buf) {
    int k0 = kt * 32;
#pragma unroll
    for (int t = 0; t < 6; ++t) {
      int idx = w * 6 + t;
      if (idx < 16) {
        int mt = idx >> 1, ks = idx & 1;
        async16(buf + idx * 1024,
                A + (size_t)(m0 + mt * 32 + l5) * 1024 + k0 + ks * 16 + q5 * 8);
      } else {
        int i2 = idx - 16, nt = i2 >> 1, ks = i2 & 1;
        async16(buf + 16384 + i2 * 1024,
                Bm + (size_t)(n0 + nt * 32 + l5) * 1024 + k0 + ks * 16 + q5 * 8);
      }
    }
  };

  auto compute = [&](const char* buf) {
#pragma unroll
    for (int ks = 0; ks < 2; ++ks) {
      bf16x8 b0 = *(const bf16x8*)(buf + 16384 + ((wc * 2 + 0) * 2 + ks) * 1024 + lane * 16);
      bf16x8 b1 = *(const bf16x8*)(buf + 16384 + ((wc * 2 + 1) * 2 + ks) * 1024 + lane * 16);
#pragma unroll
      for (int mt = 0; mt < 4; ++mt) {
        bf16x8 a = *(const bf16x8*)(buf + ((wr * 4 + mt) * 2 + ks) * 1024 + lane * 16);
        acc[mt][0] = __builtin_amdgcn_mfma_f32_32x32x16_bf16(a, b0, acc[mt][0], 0, 0, 0);
        acc[mt][1] = __builtin_amdgcn_mfma_f32_32x32x16_bf16(a, b1, acc[mt][1], 0, 0, 0);
      }
    }
  };

  char* buf0 = lds;
  char* buf1 = lds + 24576;
  stage(0, buf0);
#pragma unroll 1
  for (int kt = 0; kt < 32; kt += 2) {
    __syncthreads();
    if (kt + 1 < 32) stage(kt + 1, buf1);
    compute(buf0);
    __syncthreads();
    if (kt + 2 < 32) stage(kt + 2, buf0);
    compute(buf1);
  }

  int which = n0 >> 10;
  if (which != 2) {
    // q / k: scattered 2B stores into [b][h][s][d] (proven path).
    const float* bp = which == 0 ? bq : bk;
    unsigned short* dst = qkv + (size_t)which * 8388608;
#pragma unroll
    for (int nt = 0; nt < 2; ++nt) {
      int n_in = (n0 & 1023) + wc * 64 + nt * 32 + l5;
      float bias = bp[n_in];
      int hh = n_in >> 6, d = n_in & 63;
#pragma unroll
      for (int mt = 0; mt < 4; ++mt) {
#pragma unroll
        for (int e = 0; e < 16; ++e) {
          int m = m0 + wr * 128 + mt * 32 + (e & 3) + 8 * (e >> 2) + 4 * q5;
          int b = m >> 10, s = m & 1023;
          dst[((size_t)(b * 16 + hh) << 16) + (s << 6) + d] =
              (unsigned short)rne16(acc[mt][nt][e] + bias);
        }
      }
    }
  } else {
    // v: transpose each 32s x 32d tile in wave-private LDS, store V^T rows
    // (contiguous along s). Last LDS reads in the K-loop were from buf1
    // (offset >= 24576); wave scratch lives below 24576 -> no barrier needed.
    int b = m0 >> 10;
    unsigned short* scr = (unsigned short*)(lds) + w * 2176;  // 2 tiles x 32x34 shorts
#pragma unroll 1
    for (int mt = 0; mt < 4; ++mt) {
#pragma unroll
      for (int nt = 0; nt < 2; ++nt) {
        int n_in = (n0 & 1023) + wc * 64 + nt * 32 + l5;
        float bias = bv[n_in];
        unsigned short* tile = scr + nt * 1088;
#pragma unroll
        for (int jj = 0; jj < 8; ++jj) {
          int e = 2 * jj;
          int s_loc = (e & 3) + 8 * (e >> 2) + 4 * q5;
          *(unsigned*)(tile + l5 * 34 + s_loc) =
              packbf(acc[mt][nt][e] + bias, acc[mt][nt][e + 1] + bias);
        }
      }
      // read back s-major (lane = d-row l5, q5 = s-half) and store 32B runs.
#pragma unroll
      for (int nt = 0; nt < 2; ++nt) {
        const unsigned short* tile = scr + nt * 1088;
        unsigned di[8];
#pragma unroll
        for (int i = 0; i < 8; ++i)
          di[i] = *(const unsigned*)(tile + l5 * 34 + q5 * 16 + i * 2);
        int n_in = (n0 & 1023) + wc * 64 + nt * 32 + l5;
        int hh = n_in >> 6, dd = n_in & 63;
        int s_base = (m0 & 1023) + wr * 128 + mt * 32 + q5 * 16;
        unsigned short* dst = vt + ((size_t)(b * 16 + hh) * 64 + dd) * 1024 + s_base;
        uint4 v0 = {di[0], di[1], di[2], di[3]};
        uint4 v1 = {di[4], di[5], di[6], di[7]};
        *(uint4*)(dst) = v0;
        *(uint4*)(dst + 8) = v1;
      }
    }
  }
}

// ---------------- attention: S^T = K*Q^T, softmax (no max-sub), O^T = V^T*P ----------------
// 1024 blocks; block = (b,h, 128-qrow chunk); wave = 32 qrows. 128-key tiles,
// single-buffered K/V staging. XCD swizzle: b = blockIdx&7 so all chunks of
// one (b,h) share an XCD's L2 copy of K/V.
__global__ __launch_bounds__(256, 4) void k_attn(const unsigned short* __restrict__ qg,
                                                 const unsigned short* __restrict__ kg,
                                                 const unsigned short* __restrict__ vtg,
                                                 const float* __restrict__ maskg,
                                                 float* __restrict__ out) {
  __shared__ __align__(16) char lds[36864];
  char* KF = lds;                     // 16 KB: K fragments (128 keys x 64 dims)
  char* VF = lds + 16384;             // 16 KB: V^T fragments (64 dims x 128 keys)
  float* MK = (float*)(lds + 32768);  // 4 KB: mask row * log2(e)
  int tid = threadIdx.x, w = tid >> 6, lane = tid & 63, l5 = lane & 31, q5 = lane >> 5;
  int idx = blockIdx.x;
  int bi = idx & 7;                   // batch == XCD (round-robin dispatch heuristic)
  int j = idx >> 3;
  int h = j >> 3, qc = j & 7;
  int bh = bi * 16 + h, s0 = qc * 128;
  const unsigned short* qb = qg + ((size_t)bh << 16);
  const unsigned short* kb = kg + ((size_t)bh << 16);
  const unsigned short* vb = vtg + ((size_t)bh << 16);
  const float LG = 1.4426950408889634f;
  const float C1 = 0.125f * LG;

  {
    float4 mv = *(const float4*)(maskg + (size_t)bi * 1024 + tid * 4);
    mv.x *= LG; mv.y *= LG; mv.z *= LG; mv.w *= LG;
    *(float4*)(MK + tid * 4) = mv;
  }

  bf16x8 qfr[4];
#pragma unroll
  for (int ds = 0; ds < 4; ++ds)
    qfr[ds] = *(const bf16x8*)(qb + (size_t)(s0 + w * 32 + l5) * 64 + ds * 16 + q5 * 8);

  f32x16 O[2];
#pragma unroll
  for (int i = 0; i < 2; ++i)
#pragma unroll
    for (int e = 0; e < 16; ++e) O[i][e] = 0.f;
  float lsum = 0.f;

#pragma unroll 1
  for (int kt = 0; kt < 8; ++kt) {
    int k0 = kt * 128;
    __syncthreads();
#pragma unroll
    for (int t = 0; t < 4; ++t) {
      int f = w * 4 + t, mt = f >> 2, ds = f & 3;
      async16(KF + f * 1024, kb + (size_t)(k0 + mt * 32 + l5) * 64 + ds * 16 + q5 * 8);
    }
#pragma unroll
    for (int t = 0; t < 4; ++t) {
      int f = w * 4 + t, dt = f >> 3, ks = f & 7;
      async16(VF + f * 1024, vb + (size_t)(dt * 32 + l5) * 1024 + k0 + ks * 16 + q5 * 8);
    }
    __syncthreads();

#pragma unroll
    for (int mt = 0; mt < 4; ++mt) {
      f32x16 S;
#pragma unroll
      for (int e = 0; e < 16; ++e) S[e] = 0.f;
#pragma unroll
      for (int ds = 0; ds < 4; ++ds) {
        bf16x8 a = *(const bf16x8*)(KF + (mt * 4 + ds) * 1024 + lane * 16);
        S = __builtin_amdgcn_mfma_f32_32x32x16_bf16(a, qfr[ds], S, 0, 0, 0);
      }
      float p[16];
#pragma unroll
      for (int g4 = 0; g4 < 4; ++g4) {
        float4 mv = *(const float4*)(MK + k0 + mt * 32 + g4 * 8 + q5 * 4);
        p[g4 * 4 + 0] = __builtin_amdgcn_exp2f(S[g4 * 4 + 0] * C1 + mv.x);
        p[g4 * 4 + 1] = __builtin_amdgcn_exp2f(S[g4 * 4 + 1] * C1 + mv.y);
        p[g4 * 4 + 2] = __builtin_amdgcn_exp2f(S[g4 * 4 + 2] * C1 + mv.z);
        p[g4 * 4 + 3] = __builtin_amdgcn_exp2f(S[g4 * 4 + 3] * C1 + mv.w);
      }
      unsigned p2[8];
#pragma unroll
      for (int e = 0; e < 16; ++e) lsum += p[e];
#pragma unroll
      for (int jj = 0; jj < 8; ++jj) p2[jj] = packbf_fast(p[2 * jj], p[2 * jj + 1]);
#pragma unroll
      for (int kh = 0; kh < 2; ++kh) {
        int ks = mt * 2 + kh, gp = kh * 4;
        bf16x8 av0 = *(const bf16x8*)(VF + (0 * 8 + ks) * 1024 + lane * 16);
        bf16x8 av1 = *(const bf16x8*)(VF + (1 * 8 + ks) * 1024 + lane * 16);
        unsigned o0 = p2[gp + 0], o1 = p2[gp + 1];
        unsigned o2 = p2[gp + 2], o3 = p2[gp + 3];
        unsigned t0 = __shfl_xor((int)o0, 32);
        unsigned t1 = __shfl_xor((int)o1, 32);
        unsigned t2 = __shfl_xor((int)o2, 32);
        unsigned t3 = __shfl_xor((int)o3, 32);
        uint4 fu;
        fu.x = q5 ? t2 : o0;
        fu.y = q5 ? t3 : o1;
        fu.z = q5 ? o2 : t0;
        fu.w = q5 ? o3 : t1;
        bf16x8 bfrag = __builtin_bit_cast(bf16x8, fu);
        O[0] = __builtin_amdgcn_mfma_f32_32x32x16_bf16(av0, bfrag, O[0], 0, 0, 0);
        O[1] = __builtin_amdgcn_mfma_f32_32x32x16_bf16(av1, bfrag, O[1], 0, 0, 0);
      }
    }
  }

  // epilogue: normalize, transpose O^T via wave-private swizzled LDS, store coalesced.
  __syncthreads();
  float* Ob = (float*)(lds + w * 8192);
  float lt = lsum + __shfl_xor(lsum, 32);
  float rinv = 1.0f / lt;
#pragma unroll
  for (int dt = 0; dt < 2; ++dt)
#pragma unroll
    for (int g4 = 0; g4 < 4; ++g4) {
      float4 val;
      val.x = O[dt][g4 * 4 + 0] * rinv;
      val.y = O[dt][g4 * 4 + 1] * rinv;
      val.z = O[dt][g4 * 4 + 2] * rinv;
      val.w = O[dt][g4 * 4 + 3] * rinv;
      int c = dt * 8 + g4 * 2 + q5;
      *(float4*)(Ob + l5 * 64 + (c ^ (l5 & 15)) * 4) = val;
    }
#pragma unroll
  for (int t = 0; t < 8; ++t) {
    int qr = t * 4 + (lane >> 4), cr = lane & 15;
    float4 vv = *(const float4*)(Ob + qr * 64 + (cr ^ (qr & 15)) * 4);
    int s = s0 + w * 32 + qr;
    *(float4*)(out + (((size_t)(bi * 1024 + s)) << 10) + (h << 6) + (cr << 2)) = vv;
  }
}

extern "C" void kernel_launch(void* const* d_in, const int* in_sizes, int n_in,
                              void* d_out, int out_size, void* d_ws, size_t ws_size,
                              hipStream_t stream) {
  (void)in_sizes; (void)n_in; (void)out_size; (void)ws_size;
  const float* hidden = (const float*)d_in[0];
  const float* mask = (const float*)d_in[1];
  const float* Wq = (const float*)d_in[2];
  const float* bq = (const float*)d_in[3];
  const float* Wk = (const float*)d_in[4];
  const float* bk = (const float*)d_in[5];
  const float* Wv = (const float*)d_in[6];
  const float* bv = (const float*)d_in[7];
  float* out = (float*)d_out;
  char* ws = (char*)d_ws;
  unsigned short* hbf = (unsigned short*)ws;                  // 16,777,216 B
  unsigned short* wt  = (unsigned short*)(ws + 16777216);     //  6,291,456 B
  unsigned short* qkv = (unsigned short*)(ws + 23068672);     // 33,554,432 B (q,k)
  unsigned short* vt  = (unsigned short*)(ws + 56623104);     // 16,777,216 B (v^T)

  k_prep<<<11264, 256, 0, stream>>>(hidden, hbf, Wq, Wk, Wv, wt);
  k_gemm<<<dim3(32, 24), 256, 0, stream>>>(hbf, wt, bq, bk, bv, qkv, vt);
  k_attn<<<1024, 256, 0, stream>>>(qkv, qkv + 8388608, vt, mask, out);
}

// Round 6
// 254.471 us; speedup vs baseline: 2.5400x; 2.5400x over previous
//
#include <hip/hip_runtime.h>

// BertSelfAttention on MI355X: bf16 MFMA QKV GEMM + flash-style attention.
// B=8 S=1024 HID=1024 NH=16 HD=64. Softmax without max-subtraction (scores
// bounded ~|3.3|; exp2 safe in fp32).
// R6: fix R5's register-array demotion (V-epilogue mt loop MUST be fully
// unrolled: runtime index into acc[] demotes all 128 accumulators to scratch
// -> 3.3 GB spill traffic, 5x slowdown). Otherwise identical to R5.

typedef __bf16 bf16x8 __attribute__((ext_vector_type(8)));
typedef float f32x16 __attribute__((ext_vector_type(16)));

__device__ __forceinline__ unsigned rne16(float x) {
  unsigned u = __builtin_bit_cast(unsigned, x);
  return (u + 0x7fffu + ((u >> 16) & 1u)) >> 16;
}
__device__ __forceinline__ unsigned packbf(float lo, float hi) {
  return rne16(lo) | (rne16(hi) << 16);
}
// fast pack (round-half-up) for softmax probabilities.
__device__ __forceinline__ unsigned packbf_fast(float lo, float hi) {
  unsigned ul = __builtin_bit_cast(unsigned, lo) + 0x8000u;
  unsigned uh = __builtin_bit_cast(unsigned, hi) + 0x8000u;
  return __builtin_amdgcn_perm(uh, ul, 0x07060302u);
}
// async global->LDS, 16B per lane; LDS dst is wave-uniform base + lane*16.
__device__ __forceinline__ void async16(void* l, const void* g) {
  __builtin_amdgcn_global_load_lds((const __attribute__((address_space(1))) void*)g,
                                   (__attribute__((address_space(3))) void*)l, 16, 0, 0);
}

// ---------------- fused: hidden fp32->bf16 (blocks 0..8191) + W transpose (8192..11263) ----
__global__ __launch_bounds__(256) void k_prep(const float* __restrict__ h,
                                              unsigned short* __restrict__ hbf,
                                              const float* __restrict__ Wq,
                                              const float* __restrict__ Wk,
                                              const float* __restrict__ Wv,
                                              unsigned short* __restrict__ wt) {
  __shared__ float t[32][33];
  int bid = blockIdx.x, tid = threadIdx.x;
  if (bid < 8192) {
    size_t i = (size_t)bid * 256 + tid;
    float4 v = ((const float4*)h)[i];
    uint2 r;
    r.x = packbf(v.x, v.y);
    r.y = packbf(v.z, v.w);
    ((uint2*)hbf)[i] = r;
  } else {
    int id = bid - 8192;           // 0..3071
    int which = id >> 10;
    int sub = id & 1023;
    int c0 = (sub & 31) * 32, k0 = (sub >> 5) * 32;
    const float* W = which == 0 ? Wq : (which == 1 ? Wk : Wv);
    int tx = tid & 31, ty = tid >> 5;
#pragma unroll
    for (int i = 0; i < 4; ++i) {
      int r = ty + i * 8;
      t[r][tx] = W[(size_t)(k0 + r) * 1024 + c0 + tx];
    }
    __syncthreads();
#pragma unroll
    for (int i = 0; i < 4; ++i) {
      int r = ty + i * 8;
      wt[((size_t)which * 1024 + c0 + r) * 1024 + k0 + tx] = (unsigned short)rne16(t[tx][r]);
    }
  }
}

// ---------------- QKV GEMM: [8192x1024] x [1024x3072]^T + bias ----------------
// Block tile 256x128, wave tile 128x64 (4x2 acc), BK=32, 32x32x16 MFMA,
// double-buffered LDS (R3 structure, measured 101.8us).
// q/k written as bf16 [b][h][s][d]; v written DIRECTLY as V^T [b][h][d][s]
// via per-wave LDS transpose in the epilogue (all loops fully unrolled --
// any runtime index into acc[] demotes it to scratch).
__global__ __launch_bounds__(256, 2) void k_gemm(const unsigned short* __restrict__ A,
                                                 const unsigned short* __restrict__ Bm,
                                                 const float* __restrict__ bq,
                                                 const float* __restrict__ bk,
                                                 const float* __restrict__ bv,
                                                 unsigned short* __restrict__ qkv,
                                                 unsigned short* __restrict__ vt) {
  __shared__ __align__(16) char lds[49152];  // 2 x (A 16KB + B 8KB)
  int tid = threadIdx.x, w = tid >> 6, lane = tid & 63, l5 = lane & 31, q5 = lane >> 5;
  int wr = w >> 1, wc = w & 1;
  int m0 = blockIdx.x * 256, n0 = blockIdx.y * 128;

  f32x16 acc[4][2];
#pragma unroll
  for (int i = 0; i < 4; ++i)
#pragma unroll
    for (int j = 0; j < 2; ++j)
#pragma unroll
      for (int e = 0; e < 16; ++e) acc[i][j][e] = 0.f;

  auto stage = [&](int kt, char* buf) {
    int k0 = kt * 32;
#pragma unroll
    for (int t = 0; t < 6; ++t) {
      int idx = w * 6 + t;
      if (idx < 16) {
        int mt = idx >> 1, ks = idx & 1;
        async16(buf + idx * 1024,
                A + (size_t)(m0 + mt * 32 + l5) * 1024 + k0 + ks * 16 + q5 * 8);
      } else {
        int i2 = idx - 16, nt = i2 >> 1, ks = i2 & 1;
        async16(buf + 16384 + i2 * 1024,
                Bm + (size_t)(n0 + nt * 32 + l5) * 1024 + k0 + ks * 16 + q5 * 8);
      }
    }
  };

  auto compute = [&](const char* buf) {
#pragma unroll
    for (int ks = 0; ks < 2; ++ks) {
      bf16x8 b0 = *(const bf16x8*)(buf + 16384 + ((wc * 2 + 0) * 2 + ks) * 1024 + lane * 16);
      bf16x8 b1 = *(const bf16x8*)(buf + 16384 + ((wc * 2 + 1) * 2 + ks) * 1024 + lane * 16);
#pragma unroll
      for (int mt = 0; mt < 4; ++mt) {
        bf16x8 a = *(const bf16x8*)(buf + ((wr * 4 + mt) * 2 + ks) * 1024 + lane * 16);
        acc[mt][0] = __builtin_amdgcn_mfma_f32_32x32x16_bf16(a, b0, acc[mt][0], 0, 0, 0);
        acc[mt][1] = __builtin_amdgcn_mfma_f32_32x32x16_bf16(a, b1, acc[mt][1], 0, 0, 0);
      }
    }
  };

  char* buf0 = lds;
  char* buf1 = lds + 24576;
  stage(0, buf0);
#pragma unroll 1
  for (int kt = 0; kt < 32; kt += 2) {
    __syncthreads();
    if (kt + 1 < 32) stage(kt + 1, buf1);
    compute(buf0);
    __syncthreads();
    if (kt + 2 < 32) stage(kt + 2, buf0);
    compute(buf1);
  }

  int which = n0 >> 10;
  if (which != 2) {
    // q / k: scattered 2B stores into [b][h][s][d] (proven path).
    const float* bp = which == 0 ? bq : bk;
    unsigned short* dst = qkv + (size_t)which * 8388608;
#pragma unroll
    for (int nt = 0; nt < 2; ++nt) {
      int n_in = (n0 & 1023) + wc * 64 + nt * 32 + l5;
      float bias = bp[n_in];
      int hh = n_in >> 6, d = n_in & 63;
#pragma unroll
      for (int mt = 0; mt < 4; ++mt) {
#pragma unroll
        for (int e = 0; e < 16; ++e) {
          int m = m0 + wr * 128 + mt * 32 + (e & 3) + 8 * (e >> 2) + 4 * q5;
          int b = m >> 10, s = m & 1023;
          dst[((size_t)(b * 16 + hh) << 16) + (s << 6) + d] =
              (unsigned short)rne16(acc[mt][nt][e] + bias);
        }
      }
    }
  } else {
    // v: transpose each 32s x 32d tile in wave-private LDS, store V^T rows
    // (contiguous along s). Safe without barrier: the K-loop's final reads
    // were all from buf1 (>=24576); scratch lives below 24576; within-wave
    // DS ordering is guaranteed (compiler inserts lgkmcnt waits).
    int b = m0 >> 10;
    unsigned short* scr = (unsigned short*)(lds) + w * 2176;  // 2 tiles x 32x34 shorts
#pragma unroll
    for (int mt = 0; mt < 4; ++mt) {
#pragma unroll
      for (int nt = 0; nt < 2; ++nt) {
        int n_in = (n0 & 1023) + wc * 64 + nt * 32 + l5;
        float bias = bv[n_in];
        unsigned short* tile = scr + nt * 1088;
#pragma unroll
        for (int jj = 0; jj < 8; ++jj) {
          int e = 2 * jj;
          int s_loc = (e & 3) + 8 * (e >> 2) + 4 * q5;
          *(unsigned*)(tile + l5 * 34 + s_loc) =
              packbf(acc[mt][nt][e] + bias, acc[mt][nt][e + 1] + bias);
        }
      }
      // read back s-major (lane = d-row l5, q5 = s-half) and store 32B runs.
#pragma unroll
      for (int nt = 0; nt < 2; ++nt) {
        const unsigned short* tile = scr + nt * 1088;
        unsigned di[8];
#pragma unroll
        for (int i = 0; i < 8; ++i)
          di[i] = *(const unsigned*)(tile + l5 * 34 + q5 * 16 + i * 2);
        int n_in = (n0 & 1023) + wc * 64 + nt * 32 + l5;
        int hh = n_in >> 6, dd = n_in & 63;
        int s_base = (m0 & 1023) + wr * 128 + mt * 32 + q5 * 16;
        unsigned short* dst = vt + ((size_t)(b * 16 + hh) * 64 + dd) * 1024 + s_base;
        uint4 v0 = {di[0], di[1], di[2], di[3]};
        uint4 v1 = {di[4], di[5], di[6], di[7]};
        *(uint4*)(dst) = v0;
        *(uint4*)(dst + 8) = v1;
      }
    }
  }
}

// ---------------- attention: S^T = K*Q^T, softmax (no max-sub), O^T = V^T*P ----------------
// 1024 blocks; block = (b,h, 128-qrow chunk); wave = 32 qrows. 128-key tiles,
// single-buffered K/V staging. XCD swizzle: b = blockIdx&7 so all chunks of
// one (b,h) share an XCD's L2 copy of K/V.
__global__ __launch_bounds__(256, 4) void k_attn(const unsigned short* __restrict__ qg,
                                                 const unsigned short* __restrict__ kg,
                                                 const unsigned short* __restrict__ vtg,
                                                 const float* __restrict__ maskg,
                                                 float* __restrict__ out) {
  __shared__ __align__(16) char lds[36864];
  char* KF = lds;                     // 16 KB: K fragments (128 keys x 64 dims)
  char* VF = lds + 16384;             // 16 KB: V^T fragments (64 dims x 128 keys)
  float* MK = (float*)(lds + 32768);  // 4 KB: mask row * log2(e)
  int tid = threadIdx.x, w = tid >> 6, lane = tid & 63, l5 = lane & 31, q5 = lane >> 5;
  int idx = blockIdx.x;
  int bi = idx & 7;                   // batch == XCD (round-robin dispatch heuristic)
  int j = idx >> 3;
  int h = j >> 3, qc = j & 7;
  int bh = bi * 16 + h, s0 = qc * 128;
  const unsigned short* qb = qg + ((size_t)bh << 16);
  const unsigned short* kb = kg + ((size_t)bh << 16);
  const unsigned short* vb = vtg + ((size_t)bh << 16);
  const float LG = 1.4426950408889634f;
  const float C1 = 0.125f * LG;

  {
    float4 mv = *(const float4*)(maskg + (size_t)bi * 1024 + tid * 4);
    mv.x *= LG; mv.y *= LG; mv.z *= LG; mv.w *= LG;
    *(float4*)(MK + tid * 4) = mv;
  }

  bf16x8 qfr[4];
#pragma unroll
  for (int ds = 0; ds < 4; ++ds)
    qfr[ds] = *(const bf16x8*)(qb + (size_t)(s0 + w * 32 + l5) * 64 + ds * 16 + q5 * 8);

  f32x16 O[2];
#pragma unroll
  for (int i = 0; i < 2; ++i)
#pragma unroll
    for (int e = 0; e < 16; ++e) O[i][e] = 0.f;
  float lsum = 0.f;

#pragma unroll 1
  for (int kt = 0; kt < 8; ++kt) {
    int k0 = kt * 128;
    __syncthreads();
#pragma unroll
    for (int t = 0; t < 4; ++t) {
      int f = w * 4 + t, mt = f >> 2, ds = f & 3;
      async16(KF + f * 1024, kb + (size_t)(k0 + mt * 32 + l5) * 64 + ds * 16 + q5 * 8);
    }
#pragma unroll
    for (int t = 0; t < 4; ++t) {
      int f = w * 4 + t, dt = f >> 3, ks = f & 7;
      async16(VF + f * 1024, vb + (size_t)(dt * 32 + l5) * 1024 + k0 + ks * 16 + q5 * 8);
    }
    __syncthreads();

#pragma unroll
    for (int mt = 0; mt < 4; ++mt) {
      f32x16 S;
#pragma unroll
      for (int e = 0; e < 16; ++e) S[e] = 0.f;
#pragma unroll
      for (int ds = 0; ds < 4; ++ds) {
        bf16x8 a = *(const bf16x8*)(KF + (mt * 4 + ds) * 1024 + lane * 16);
        S = __builtin_amdgcn_mfma_f32_32x32x16_bf16(a, qfr[ds], S, 0, 0, 0);
      }
      float p[16];
#pragma unroll
      for (int g4 = 0; g4 < 4; ++g4) {
        float4 mv = *(const float4*)(MK + k0 + mt * 32 + g4 * 8 + q5 * 4);
        p[g4 * 4 + 0] = __builtin_amdgcn_exp2f(S[g4 * 4 + 0] * C1 + mv.x);
        p[g4 * 4 + 1] = __builtin_amdgcn_exp2f(S[g4 * 4 + 1] * C1 + mv.y);
        p[g4 * 4 + 2] = __builtin_amdgcn_exp2f(S[g4 * 4 + 2] * C1 + mv.z);
        p[g4 * 4 + 3] = __builtin_amdgcn_exp2f(S[g4 * 4 + 3] * C1 + mv.w);
      }
      unsigned p2[8];
#pragma unroll
      for (int e = 0; e < 16; ++e) lsum += p[e];
#pragma unroll
      for (int jj = 0; jj < 8; ++jj) p2[jj] = packbf_fast(p[2 * jj], p[2 * jj + 1]);
#pragma unroll
      for (int kh = 0; kh < 2; ++kh) {
        int ks = mt * 2 + kh, gp = kh * 4;
        bf16x8 av0 = *(const bf16x8*)(VF + (0 * 8 + ks) * 1024 + lane * 16);
        bf16x8 av1 = *(const bf16x8*)(VF + (1 * 8 + ks) * 1024 + lane * 16);
        unsigned o0 = p2[gp + 0], o1 = p2[gp + 1];
        unsigned o2 = p2[gp + 2], o3 = p2[gp + 3];
        unsigned t0 = __shfl_xor((int)o0, 32);
        unsigned t1 = __shfl_xor((int)o1, 32);
        unsigned t2 = __shfl_xor((int)o2, 32);
        unsigned t3 = __shfl_xor((int)o3, 32);
        uint4 fu;
        fu.x = q5 ? t2 : o0;
        fu.y = q5 ? t3 : o1;
        fu.z = q5 ? o2 : t0;
        fu.w = q5 ? o3 : t1;
        bf16x8 bfrag = __builtin_bit_cast(bf16x8, fu);
        O[0] = __builtin_amdgcn_mfma_f32_32x32x16_bf16(av0, bfrag, O[0], 0, 0, 0);
        O[1] = __builtin_amdgcn_mfma_f32_32x32x16_bf16(av1, bfrag, O[1], 0, 0, 0);
      }
    }
  }

  // epilogue: normalize, transpose O^T via wave-private swizzled LDS, store coalesced.
  __syncthreads();
  float* Ob = (float*)(lds + w * 8192);
  float lt = lsum + __shfl_xor(lsum, 32);
  float rinv = 1.0f / lt;
#pragma unroll
  for (int dt = 0; dt < 2; ++dt)
#pragma unroll
    for (int g4 = 0; g4 < 4; ++g4) {
      float4 val;
      val.x = O[dt][g4 * 4 + 0] * rinv;
      val.y = O[dt][g4 * 4 + 1] * rinv;
      val.z = O[dt][g4 * 4 + 2] * rinv;
      val.w = O[dt][g4 * 4 + 3] * rinv;
      int c = dt * 8 + g4 * 2 + q5;
      *(float4*)(Ob + l5 * 64 + (c ^ (l5 & 15)) * 4) = val;
    }
#pragma unroll
  for (int t = 0; t < 8; ++t) {
    int qr = t * 4 + (lane >> 4), cr = lane & 15;
    float4 vv = *(const float4*)(Ob + qr * 64 + (cr ^ (qr & 15)) * 4);
    int s = s0 + w * 32 + qr;
    *(float4*)(out + (((size_t)(bi * 1024 + s)) << 10) + (h << 6) + (cr << 2)) = vv;
  }
}

extern "C" void kernel_launch(void* const* d_in, const int* in_sizes, int n_in,
                              void* d_out, int out_size, void* d_ws, size_t ws_size,
                              hipStream_t stream) {
  (void)in_sizes; (void)n_in; (void)out_size; (void)ws_size;
  const float* hidden = (const float*)d_in[0];
  const float* mask = (const float*)d_in[1];
  const float* Wq = (const float*)d_in[2];
  const float* bq = (const float*)d_in[3];
  const float* Wk = (const float*)d_in[4];
  const float* bk = (const float*)d_in[5];
  const float* Wv = (const float*)d_in[6];
  const float* bv = (const float*)d_in[7];
  float* out = (float*)d_out;
  char* ws = (char*)d_ws;
  unsigned short* hbf = (unsigned short*)ws;                  // 16,777,216 B
  unsigned short* wt  = (unsigned short*)(ws + 16777216);     //  6,291,456 B
  unsigned short* qkv = (unsigned short*)(ws + 23068672);     // 33,554,432 B (q,k)
  unsigned short* vt  = (unsigned short*)(ws + 56623104);     // 16,777,216 B (v^T)

  k_prep<<<11264, 256, 0, stream>>>(hidden, hbf, Wq, Wk, Wv, wt);
  k_gemm<<<dim3(32, 24), 256, 0, stream>>>(hbf, wt, bq, bk, bv, qkv, vt);
  k_attn<<<1024, 256, 0, stream>>>(qkv, qkv + 8388608, vt, mask, out);
}